// Round 2
// baseline (417.757 us; speedup 1.0000x reference)
//
#include <hip/hip_runtime.h>
#include <hip/hip_bf16.h>
#include <math.h>

#define B_  4
#define C_  128
#define W_  4096
#define CH_ 64

typedef __bf16 bf16;
typedef __attribute__((ext_vector_type(8))) __bf16 bf16x8;
typedef __attribute__((ext_vector_type(4))) __bf16 bf16x4;
typedef __attribute__((ext_vector_type(4))) float f32x4;
typedef __attribute__((ext_vector_type(4))) short short4v;

__device__ __forceinline__ f32x4 mfma32bf(bf16x8 a, bf16x8 b, f32x4 c) {
    return __builtin_amdgcn_mfma_f32_16x16x32_bf16(a, b, c, 0, 0, 0);
}
__device__ __forceinline__ f32x4 mfma16bf(bf16x4 a, short4v b, f32x4 c) {
    return __builtin_amdgcn_mfma_f32_16x16x16bf16_1k(__builtin_bit_cast(short4v, a), b, c, 0, 0, 0);
}

// ---------------------------------------------------------------------------
// Projection: Q = Wq*x + bq, K = Wk*x + bk  (fp32, then split bf16 hi/lo),
//             V = bf16(x) kept in x's native [b][c][w] layout.
// Layouts in ws:  Qh/Ql/Kh/Kl : [B][W][64] bf16 ;  Vb : [B][128][W] bf16
// ---------------------------------------------------------------------------
__global__ __launch_bounds__(256) void proj_kernel(
    const float* __restrict__ x,
    const float* __restrict__ Wq, const float* __restrict__ bq,
    const float* __restrict__ Wk, const float* __restrict__ bk,
    bf16* __restrict__ Qh, bf16* __restrict__ Ql,
    bf16* __restrict__ Kh, bf16* __restrict__ Kl,
    bf16* __restrict__ Vb)
{
    __shared__ float xt[C_][64];          // [c][w] tile, reads are wave-broadcast
    __shared__ float WqL[CH_][C_ + 1];    // +1 pad: o-stride 129 -> 2-way banks
    __shared__ float WkL[CH_][C_ + 1];

    const int t  = threadIdx.x;
    const int b  = blockIdx.x >> 6;           // W_/64 = 64 blocks per batch
    const int w0 = (blockIdx.x & 63) << 6;

    const size_t xbase = (size_t)b * C_ * W_ + w0;
    #pragma unroll
    for (int k = 0; k < 32; ++k) {
        int idx = t + k * 256;
        int c = idx >> 6, w = idx & 63;
        float v = x[xbase + (size_t)c * W_ + w];
        xt[c][w] = v;
        Vb[xbase + (size_t)c * W_ + w] = (bf16)v;   // V cast on the way through
    }
    #pragma unroll
    for (int k = 0; k < 32; ++k) {
        int idx = t + k * 256;
        int o = idx >> 7, c = idx & 127;
        WqL[o][c] = Wq[idx];
        WkL[o][c] = Wk[idx];
    }
    __syncthreads();

    const int o  = t & 63;    // lane = output channel -> coalesced stores
    const int wg = t >> 6;    // wave-uniform w-subgroup (16 w's)

    float accq[16], acck[16];
    const float bqv = bq[o], bkv = bk[o];
    #pragma unroll
    for (int i = 0; i < 16; ++i) { accq[i] = bqv; acck[i] = bkv; }

    #pragma unroll 2
    for (int c = 0; c < C_; ++c) {
        const float wq = WqL[o][c];
        const float wk = WkL[o][c];
        float xv[16];
        *(float4*)&xv[0]  = *(const float4*)&xt[c][wg * 16 + 0];
        *(float4*)&xv[4]  = *(const float4*)&xt[c][wg * 16 + 4];
        *(float4*)&xv[8]  = *(const float4*)&xt[c][wg * 16 + 8];
        *(float4*)&xv[12] = *(const float4*)&xt[c][wg * 16 + 12];
        #pragma unroll
        for (int i = 0; i < 16; ++i) {
            accq[i] = fmaf(wq, xv[i], accq[i]);
            acck[i] = fmaf(wk, xv[i], acck[i]);
        }
    }

    const size_t qbase = ((size_t)b * W_ + w0) * CH_ + o;
    #pragma unroll
    for (int i = 0; i < 16; ++i) {
        const int w = wg * 16 + i;
        float q  = accq[i];
        bf16 qhv = (bf16)q;
        bf16 qlv = (bf16)(q - (float)qhv);   // exact residual, fits bf16
        float kv = acck[i];
        bf16 khv = (bf16)kv;
        bf16 klv = (bf16)(kv - (float)khv);
        Qh[qbase + (size_t)w * CH_] = qhv;
        Ql[qbase + (size_t)w * CH_] = qlv;
        Kh[qbase + (size_t)w * CH_] = khv;
        Kl[qbase + (size_t)w * CH_] = klv;
    }
}

// ---------------------------------------------------------------------------
// Flash attention. 1 wave per 16 query rows. E^T = mfma(K,Q) (swapped operands
// so the k-mapping of the 16x16x32 A/B fragments cancels); online softmax in
// registers; P^T feeds mfma_16x16x16 B-operand directly (acc layout == B
// layout); O^T = mfma(V^T, P^T) accumulates straight into d_out's layout.
// ---------------------------------------------------------------------------
#define LOADK(S, J) { \
    const bf16* kr_ = Khb + (size_t)(J) * CH_; \
    kh0##S = *(const bf16x8*)(kr_); \
    kh1##S = *(const bf16x8*)(kr_ + 32); \
    const bf16* lr_ = Klb + (size_t)(J) * CH_; \
    kl0##S = *(const bf16x8*)(lr_); \
    kl1##S = *(const bf16x8*)(lr_ + 32); }

#define LOADV(S, J) { \
    _Pragma("unroll") \
    for (int tt = 0; tt < 8; ++tt) \
        v##S[tt] = *(const bf16x4*)(Vbb + (size_t)(tt * 16) * W_ + (J)); }

#define STEP(S) { \
    f32x4 e = {0.f, 0.f, 0.f, 0.f}; \
    e = mfma32bf(kh0##S, qh0, e); \
    e = mfma32bf(kl0##S, qh0, e); \
    e = mfma32bf(kh0##S, ql0, e); \
    e = mfma32bf(kh1##S, qh1, e); \
    e = mfma32bf(kl1##S, qh1, e); \
    e = mfma32bf(kh1##S, ql1, e); \
    float mt = fmaxf(fmaxf(e[0], e[1]), fmaxf(e[2], e[3])); \
    mt = fmaxf(mt, __shfl_xor(mt, 16)); \
    mt = fmaxf(mt, __shfl_xor(mt, 32)); \
    if (__any(mt > m)) { \
        const float mn = fmaxf(m, mt); \
        const float sc = __expf(m - mn); \
        l *= sc; \
        _Pragma("unroll") \
        for (int t8 = 0; t8 < 8; ++t8) { \
            oacc[t8][0] *= sc; oacc[t8][1] *= sc; \
            oacc[t8][2] *= sc; oacc[t8][3] *= sc; } \
        m = mn; \
    } \
    const float p0 = __expf(e[0] - m); \
    const float p1 = __expf(e[1] - m); \
    const float p2 = __expf(e[2] - m); \
    const float p3 = __expf(e[3] - m); \
    l += (p0 + p1) + (p2 + p3); \
    bf16x4 pb; pb[0] = (bf16)p0; pb[1] = (bf16)p1; pb[2] = (bf16)p2; pb[3] = (bf16)p3; \
    const short4v ps = __builtin_bit_cast(short4v, pb); \
    _Pragma("unroll") \
    for (int t8 = 0; t8 < 8; ++t8) \
        oacc[t8] = mfma16bf(v##S[t8], ps, oacc[t8]); }

__global__ __launch_bounds__(64) void attn_kernel(
    const bf16* __restrict__ Qh, const bf16* __restrict__ Ql,
    const bf16* __restrict__ Kh, const bf16* __restrict__ Kl,
    const bf16* __restrict__ Vb, float* __restrict__ out)
{
    const int lane = threadIdx.x;
    const int li = lane & 15;
    const int gi = lane >> 4;

    // bijective XCD swizzle: each XCD gets 128 consecutive logical blocks
    // (= half a batch, ~3MB working set -> fits its 4MB L2). 1024 % 8 == 0.
    const int nwg = B_ * (W_ / 16);            // 1024
    const int bid = blockIdx.x;
    const int swz = (bid & 7) * (nwg / 8) + (bid >> 3);
    const int b   = swz >> 8;                  // 256 i-blocks per batch
    const int i0  = (swz & 255) << 4;

    // hoist Q fragments (B-operand: col = li, 8 contiguous k at 8*gi)
    const bf16* qhr = Qh + ((size_t)b * W_ + i0 + li) * CH_ + 8 * gi;
    const bf16* qlr = Ql + ((size_t)b * W_ + i0 + li) * CH_ + 8 * gi;
    const bf16x8 qh0 = *(const bf16x8*)(qhr);
    const bf16x8 qh1 = *(const bf16x8*)(qhr + 32);
    const bf16x8 ql0 = *(const bf16x8*)(qlr);
    const bf16x8 ql1 = *(const bf16x8*)(qlr + 32);

    const bf16* Khb = Kh + (size_t)b * W_ * CH_ + (size_t)li * CH_ + 8 * gi;
    const bf16* Klb = Kl + (size_t)b * W_ * CH_ + (size_t)li * CH_ + 8 * gi;
    const bf16* Vbb = Vb + (size_t)b * C_ * W_ + (size_t)li * W_ + 4 * gi;

    f32x4 oacc[8];
    #pragma unroll
    for (int t8 = 0; t8 < 8; ++t8) oacc[t8] = (f32x4){0.f, 0.f, 0.f, 0.f};
    float m = -INFINITY;
    float l = 0.f;

    bf16x8 kh0A, kh1A, kl0A, kl1A, kh0B, kh1B, kl0B, kl1B;
    bf16x4 vA[8], vB[8];

    LOADK(A, 0) LOADV(A, 0)
    #pragma unroll 1
    for (int js = 0; js < 254; js += 2) {
        LOADK(B, (js + 1) * 16) LOADV(B, (js + 1) * 16)
        STEP(A)
        LOADK(A, (js + 2) * 16) LOADV(A, (js + 2) * 16)
        STEP(B)
    }
    LOADK(B, 255 * 16) LOADV(B, 255 * 16)
    STEP(A)
    STEP(B)

    // total row sum across the 4 lane-groups (each owns 4 of every 16 keys)
    l += __shfl_xor(l, 16);
    l += __shfl_xor(l, 32);
    const float inv = 1.0f / l;

    // O^T acc: row = c = t8*16 + 4*gi + r, col = i = li  -> matches d_out
    float* ob = out + (size_t)b * C_ * W_ + i0 + li;
    #pragma unroll
    for (int t8 = 0; t8 < 8; ++t8) {
        const int c0 = t8 * 16 + gi * 4;
        ob[(size_t)(c0 + 0) * W_] = oacc[t8][0] * inv;
        ob[(size_t)(c0 + 1) * W_] = oacc[t8][1] * inv;
        ob[(size_t)(c0 + 2) * W_] = oacc[t8][2] * inv;
        ob[(size_t)(c0 + 3) * W_] = oacc[t8][3] * inv;
    }
}

extern "C" void kernel_launch(void* const* d_in, const int* in_sizes, int n_in,
                              void* d_out, int out_size, void* d_ws, size_t ws_size,
                              hipStream_t stream)
{
    (void)in_sizes; (void)n_in; (void)out_size; (void)ws_size;

    const float* x  = (const float*)d_in[0];
    const float* Wq = (const float*)d_in[1];
    const float* bq = (const float*)d_in[2];
    const float* Wk = (const float*)d_in[3];
    const float* bk = (const float*)d_in[4];
    float* out = (float*)d_out;

    // ws layout (12 MB total): Qh,Ql,Kh,Kl: 2MB each ; Vb: 4MB
    char* ws = (char*)d_ws;
    const size_t MB = 1024 * 1024;
    bf16* Qh = (bf16*)(ws + 0 * MB);
    bf16* Ql = (bf16*)(ws + 2 * MB);
    bf16* Kh = (bf16*)(ws + 4 * MB);
    bf16* Kl = (bf16*)(ws + 6 * MB);
    bf16* Vb = (bf16*)(ws + 8 * MB);

    proj_kernel<<<dim3(B_ * (W_ / 64)), dim3(256), 0, stream>>>(
        x, Wq, bq, Wk, bk, Qh, Ql, Kh, Kl, Vb);
    attn_kernel<<<dim3(B_ * (W_ / 16)), dim3(64), 0, stream>>>(
        Qh, Ql, Kh, Kl, Vb, out);
}

// Round 3
// 208.564 us; speedup vs baseline: 2.0030x; 2.0030x over previous
//
#include <hip/hip_runtime.h>
#include <hip/hip_bf16.h>
#include <math.h>

#define B_  4
#define C_  128
#define W_  4096
#define CH_ 64

typedef __bf16 bf16;
typedef __attribute__((ext_vector_type(8))) __bf16 bf16x8;
typedef __attribute__((ext_vector_type(4))) __bf16 bf16x4;
typedef __attribute__((ext_vector_type(4))) float f32x4;
typedef __attribute__((ext_vector_type(4))) short short4v;

__device__ __forceinline__ f32x4 mfma32bf(bf16x8 a, bf16x8 b, f32x4 c) {
    return __builtin_amdgcn_mfma_f32_16x16x32_bf16(a, b, c, 0, 0, 0);
}
__device__ __forceinline__ f32x4 mfma16bf(bf16x4 a, short4v b, f32x4 c) {
    return __builtin_amdgcn_mfma_f32_16x16x16bf16_1k(__builtin_bit_cast(short4v, a), b, c, 0, 0, 0);
}

// ---------------------------------------------------------------------------
// Fragment-major scratch layouts (per batch, per 16-key block "jblk"):
//   Kfrag: [b][jblk][ kh0 | kh1 | kl0 | kl1 ]  each chunk = 64 lanes x 8 bf16
//          chunk kh0/kl0: lane l -> K[j=jblk*16+(l&15)][ch=8*(l>>4)+0..7]
//          chunk kh1/kl1: same with ch += 32
//   Vfrag: [b][jblk][ tt=0..7 ] each chunk = 64 lanes x 4 bf16
//          lane l -> x_bf16[c=tt*16+(l&15)][w=jblk*16+4*(l>>4)+0..3]
// => the attn wave's whole 8KB step-tile is 12 contiguous vector loads.
// ---------------------------------------------------------------------------

__global__ __launch_bounds__(256) void proj_kernel(
    const float* __restrict__ x,
    const float* __restrict__ Wq, const float* __restrict__ bq,
    const float* __restrict__ Wk, const float* __restrict__ bk,
    bf16* __restrict__ Qh, bf16* __restrict__ Ql,
    bf16* __restrict__ Kfrag, bf16* __restrict__ Vfrag)
{
    __shared__ float xt[C_][68];          // stride 68: 16B-aligned rows, few conflicts
    __shared__ float WqL[CH_][C_ + 1];
    __shared__ float WkL[CH_][C_ + 1];

    const int t  = threadIdx.x;
    const int b  = blockIdx.x >> 6;           // 64 blocks per batch
    const int w0 = (blockIdx.x & 63) << 6;

    const size_t xbase = (size_t)b * C_ * W_ + w0;
    #pragma unroll
    for (int k = 0; k < 32; ++k) {
        int idx = t + k * 256;
        int c = idx >> 6, w = idx & 63;
        xt[c][w] = x[xbase + (size_t)c * W_ + w];
    }
    #pragma unroll
    for (int k = 0; k < 32; ++k) {
        int idx = t + k * 256;
        int o = idx >> 7, c = idx & 127;
        WqL[o][c] = Wq[idx];
        WkL[o][c] = Wk[idx];
    }
    __syncthreads();

    const int o  = t & 63;    // lane = output channel
    const int wg = t >> 6;    // wave id = 16-w subgroup = local jblk

    float accq[16], acck[16];
    const float bqv = bq[o], bkv = bk[o];
    #pragma unroll
    for (int i = 0; i < 16; ++i) { accq[i] = bqv; acck[i] = bkv; }

    #pragma unroll 2
    for (int c = 0; c < C_; ++c) {
        const float wq = WqL[o][c];
        const float wk = WkL[o][c];
        float xv[16];
        *(float4*)&xv[0]  = *(const float4*)&xt[c][wg * 16 + 0];
        *(float4*)&xv[4]  = *(const float4*)&xt[c][wg * 16 + 4];
        *(float4*)&xv[8]  = *(const float4*)&xt[c][wg * 16 + 8];
        *(float4*)&xv[12] = *(const float4*)&xt[c][wg * 16 + 12];
        #pragma unroll
        for (int i = 0; i < 16; ++i) {
            accq[i] = fmaf(wq, xv[i], accq[i]);
            acck[i] = fmaf(wk, xv[i], acck[i]);
        }
    }

    // ---- Q: keep [b][w][64] layout (read once per wave in attn) ----
    const size_t qbase = ((size_t)b * W_ + w0) * CH_ + o;
    // ---- K: direct scattered fragment stores (fire-and-forget) ----
    const int jblk0 = (w0 >> 4) + wg;         // constant per thread
    const size_t kconst = (size_t)b * 524288 + (size_t)jblk0 * 2048
                        + (size_t)(o >> 5) * 512 + (size_t)((o >> 3) & 3) * 128
                        + (o & 7);
    #pragma unroll
    for (int i = 0; i < 16; ++i) {
        const int w = wg * 16 + i;
        float q  = accq[i];
        bf16 qhv = (bf16)q;
        bf16 qlv = (bf16)(q - (float)qhv);
        float kv = acck[i];
        bf16 khv = (bf16)kv;
        bf16 klv = (bf16)(kv - (float)khv);
        Qh[qbase + (size_t)w * CH_] = qhv;
        Ql[qbase + (size_t)w * CH_] = qlv;
        Kfrag[kconst + i * 8]        = khv;
        Kfrag[kconst + i * 8 + 1024] = klv;
    }

    // ---- V fragments from xt (already barriered above) ----
    const int l = o;  // lane within wave
    bf16* vfb = Vfrag + (size_t)b * 524288 + (size_t)jblk0 * 2048;
    #pragma unroll
    for (int tt = 0; tt < 8; ++tt) {
        const float4 xv4 = *(const float4*)&xt[tt * 16 + (l & 15)][wg * 16 + 4 * (l >> 4)];
        bf16x4 vb4;
        vb4[0] = (bf16)xv4.x; vb4[1] = (bf16)xv4.y;
        vb4[2] = (bf16)xv4.z; vb4[3] = (bf16)xv4.w;
        *(bf16x4*)(vfb + tt * 256 + l * 4) = vb4;
    }
}

// ---------------------------------------------------------------------------
// Flash attention, 1 wave / 16 query rows. All hot-loop loads coalesced from
// fragment-major buffers; triple-buffered register prefetch (2 steps ahead).
// ---------------------------------------------------------------------------
#define LOADK(S, JB) { \
    const bf16* kp_ = KB + (size_t)(JB) * 2048; \
    kh0##S = *(const bf16x8*)(kp_); \
    kh1##S = *(const bf16x8*)(kp_ + 512); \
    kl0##S = *(const bf16x8*)(kp_ + 1024); \
    kl1##S = *(const bf16x8*)(kp_ + 1536); }

#define LOADV(S, JB) { \
    const bf16* vp_ = VB + (size_t)(JB) * 2048; \
    _Pragma("unroll") \
    for (int tt = 0; tt < 8; ++tt) \
        v##S[tt] = *(const bf16x4*)(vp_ + tt * 256); }

#define STEP(S) { \
    f32x4 e = {0.f, 0.f, 0.f, 0.f}; \
    e = mfma32bf(kh0##S, qh0, e); \
    e = mfma32bf(kl0##S, qh0, e); \
    e = mfma32bf(kh0##S, ql0, e); \
    e = mfma32bf(kh1##S, qh1, e); \
    e = mfma32bf(kl1##S, qh1, e); \
    e = mfma32bf(kh1##S, ql1, e); \
    float mt = fmaxf(fmaxf(e[0], e[1]), fmaxf(e[2], e[3])); \
    mt = fmaxf(mt, __shfl_xor(mt, 16)); \
    mt = fmaxf(mt, __shfl_xor(mt, 32)); \
    if (__any(mt > m)) { \
        const float mn = fmaxf(m, mt); \
        const float sc = __expf(m - mn); \
        l *= sc; \
        _Pragma("unroll") \
        for (int t8 = 0; t8 < 8; ++t8) { \
            oacc[t8][0] *= sc; oacc[t8][1] *= sc; \
            oacc[t8][2] *= sc; oacc[t8][3] *= sc; } \
        m = mn; \
    } \
    const float p0 = __expf(e[0] - m); \
    const float p1 = __expf(e[1] - m); \
    const float p2 = __expf(e[2] - m); \
    const float p3 = __expf(e[3] - m); \
    l += (p0 + p1) + (p2 + p3); \
    bf16x4 pb; pb[0] = (bf16)p0; pb[1] = (bf16)p1; pb[2] = (bf16)p2; pb[3] = (bf16)p3; \
    const short4v ps = __builtin_bit_cast(short4v, pb); \
    _Pragma("unroll") \
    for (int t8 = 0; t8 < 8; ++t8) \
        oacc[t8] = mfma16bf(v##S[t8], ps, oacc[t8]); }

__global__ __launch_bounds__(64) void attn_kernel(
    const bf16* __restrict__ Qh, const bf16* __restrict__ Ql,
    const bf16* __restrict__ Kfrag, const bf16* __restrict__ Vfrag,
    float* __restrict__ out)
{
    const int lane = threadIdx.x;
    const int li = lane & 15;
    const int gi = lane >> 4;

    // bijective XCD swizzle: each XCD streams half a batch (~2MB, L2-resident)
    const int nwg = B_ * (W_ / 16);            // 1024
    const int bid = blockIdx.x;
    const int swz = (bid & 7) * (nwg / 8) + (bid >> 3);
    const int b   = swz >> 8;
    const int i0  = (swz & 255) << 4;

    const bf16* qhr = Qh + ((size_t)b * W_ + i0 + li) * CH_ + 8 * gi;
    const bf16* qlr = Ql + ((size_t)b * W_ + i0 + li) * CH_ + 8 * gi;
    const bf16x8 qh0 = *(const bf16x8*)(qhr);
    const bf16x8 qh1 = *(const bf16x8*)(qhr + 32);
    const bf16x8 ql0 = *(const bf16x8*)(qlr);
    const bf16x8 ql1 = *(const bf16x8*)(qlr + 32);

    const bf16* KB = Kfrag + (size_t)b * 524288 + (size_t)lane * 8;
    const bf16* VB = Vfrag + (size_t)b * 524288 + (size_t)lane * 4;

    f32x4 oacc[8];
    #pragma unroll
    for (int t8 = 0; t8 < 8; ++t8) oacc[t8] = (f32x4){0.f, 0.f, 0.f, 0.f};
    float m = -INFINITY;
    float l = 0.f;

    bf16x8 kh0A, kh1A, kl0A, kl1A, kh0B, kh1B, kl0B, kl1B, kh0C, kh1C, kl0C, kl1C;
    bf16x4 vA[8], vB[8], vC[8];

    LOADK(A, 0) LOADV(A, 0)
    LOADK(B, 1) LOADV(B, 1)
    #pragma unroll 1
    for (int js = 0; js < 252; js += 3) {
        LOADK(C, js + 2) LOADV(C, js + 2)
        STEP(A)
        LOADK(A, js + 3) LOADV(A, js + 3)
        STEP(B)
        LOADK(B, js + 4) LOADV(B, js + 4)
        STEP(C)
    }
    // after loop: A=252, B=253 loaded
    LOADK(C, 254) LOADV(C, 254)
    STEP(A)
    LOADK(A, 255) LOADV(A, 255)
    STEP(B)
    STEP(C)
    STEP(A)

    l += __shfl_xor(l, 16);
    l += __shfl_xor(l, 32);
    const float inv = 1.0f / l;

    float* ob = out + (size_t)b * C_ * W_ + i0 + li;
    #pragma unroll
    for (int t8 = 0; t8 < 8; ++t8) {
        const int c0 = t8 * 16 + gi * 4;
        ob[(size_t)(c0 + 0) * W_] = oacc[t8][0] * inv;
        ob[(size_t)(c0 + 1) * W_] = oacc[t8][1] * inv;
        ob[(size_t)(c0 + 2) * W_] = oacc[t8][2] * inv;
        ob[(size_t)(c0 + 3) * W_] = oacc[t8][3] * inv;
    }
}

extern "C" void kernel_launch(void* const* d_in, const int* in_sizes, int n_in,
                              void* d_out, int out_size, void* d_ws, size_t ws_size,
                              hipStream_t stream)
{
    (void)in_sizes; (void)n_in; (void)out_size; (void)ws_size;

    const float* x  = (const float*)d_in[0];
    const float* Wq = (const float*)d_in[1];
    const float* bq = (const float*)d_in[2];
    const float* Wk = (const float*)d_in[3];
    const float* bk = (const float*)d_in[4];
    float* out = (float*)d_out;

    // ws layout (12 MB): Qh 2MB | Ql 2MB | Kfrag 4MB | Vfrag 4MB
    char* ws = (char*)d_ws;
    const size_t MB = 1024 * 1024;
    bf16* Qh    = (bf16*)(ws + 0 * MB);
    bf16* Ql    = (bf16*)(ws + 2 * MB);
    bf16* Kfrag = (bf16*)(ws + 4 * MB);
    bf16* Vfrag = (bf16*)(ws + 8 * MB);

    proj_kernel<<<dim3(B_ * (W_ / 64)), dim3(256), 0, stream>>>(
        x, Wq, bq, Wk, bk, Qh, Ql, Kfrag, Vfrag);
    attn_kernel<<<dim3(B_ * (W_ / 16)), dim3(64), 0, stream>>>(
        Qh, Ql, Kfrag, Vfrag, out);
}